// Round 5
// baseline (729.950 us; speedup 1.0000x reference)
//
#include <hip/hip_runtime.h>
#include <math.h>

#define T_     4096
#define BH_    64
#define EPS_   1e-6f
#define SCALE_ 0.0625f   // 1/sqrt(256)

typedef _Float16 h16;
typedef __attribute__((ext_vector_type(2))) _Float16 h16x2;
typedef __attribute__((ext_vector_type(4))) _Float16 h16x4;
typedef __attribute__((ext_vector_type(8))) _Float16 h16x8;
typedef __attribute__((ext_vector_type(2))) __fp16   fp16x2r;   // raw builtin return type
typedef __attribute__((ext_vector_type(4))) short    short4v;
typedef __attribute__((ext_vector_type(8))) short    bf16x8;
typedef __attribute__((ext_vector_type(4))) float    f32x4;

__device__ __forceinline__ h16x2 pkrtz(float a, float b) {
    fp16x2r r = __builtin_amdgcn_cvt_pkrtz(a, b);
    h16x2 o; o.x = (h16)r.x; o.y = (h16)r.y;
    return o;
}

__device__ __forceinline__ void bfsplit(float x, short& h, short& l) {
    unsigned u = __float_as_uint(x) + 0x8000u;       // round-half-up to bf16
    unsigned hb = u & 0xffff0000u;
    h = (short)(u >> 16);
    float lf = x - __uint_as_float(hb);              // exact residual
    l = (short)(__float_as_uint(lf) >> 16);          // truncated residual
}
// pack bf16(a) (low) | bf16(b) (high), round-half-up; returns residual bit patterns
__device__ __forceinline__ unsigned pk_hi2(float a, float b, unsigned& ra, unsigned& rb) {
    unsigned ua = __float_as_uint(a) + 0x8000u;
    unsigned ub = __float_as_uint(b) + 0x8000u;
    ra = ua & 0xffff0000u; rb = ub & 0xffff0000u;
    return __builtin_amdgcn_perm(ub, ua, 0x07060302u);
}
__device__ __forceinline__ unsigned pk_tr2(float a, float b) {   // truncating pack
    return __builtin_amdgcn_perm(__float_as_uint(b), __float_as_uint(a), 0x07060302u);
}

// ============================================================
// prep: W (64x256) -> W^T padded f16 hi/lo planes [256][72]
// ============================================================
__global__ __launch_bounds__(256)
void k_prep(const float* __restrict__ Wg, h16* __restrict__ wtp)
{
    int d = blockIdx.x;      // 0..63
    int r = threadIdx.x;     // 0..255
    float x = Wg[d * 256 + r];
    h16 hi = (h16)x;
    h16 lo = (h16)(x - (float)hi);
    wtp[r * 72 + d]            = hi;
    wtp[256 * 72 + r * 72 + d] = lo;
}

// ============================================================
// Stage 1: per (t-chunk s, head bh). k,v staged to LDS (split/bf16-split),
// proj f16x3 MFMA -> exp -> kv bf16x3 MFMA. Reg-prefetch next chunk.
// 8 waves: (tg 0..1 t-half) x (rg 0..3 r-strip). 2 barriers/chunk.
// ============================================================
__global__ __launch_bounds__(512, 2)
void k_stage1(const float* __restrict__ kg, const float* __restrict__ vg,
              const float* __restrict__ mg, const h16* __restrict__ wtp,
              float* __restrict__ kv_part, float* __restrict__ ks_part, int nch)
{
    __shared__ __align__(16) char smem[148480];
    h16*   Wt   = (h16*)smem;                       // [2][256*72]   73728 B
    h16*   kT0  = (h16*)(smem + 73728);             // [128*72]      18432 B
    h16*   kT1  = (h16*)(smem + 92160);             // [128*72]      18432 B
    short* vTh  = (short*)(smem + 110592);          // [64*136]      17408 B
    short* vTl  = (short*)(smem + 128000);          // [64*136]      17408 B
    float* np2  = (float*)(smem + 145408);          // [128]           512 B
    float* mskl = (float*)(smem + 145920);          // [128]           512 B
    float* ksb  = (float*)(smem + 146432);          // [2][256]       2048 B
    float* red  = (float*)(smem + 73728);           // alias kT/vT: 256*68*4 = 69632 B

    const int tid  = threadIdx.x;
    const int lane = tid & 63, l15 = lane & 15, q = lane >> 4;
    const int wid  = tid >> 6;
    const int rg = wid & 3, tg = wid >> 2;
    const int s = blockIdx.x, bh = blockIdx.y, b = bh >> 4;
    const long rowb = (long)bh * T_;
    const int tcb = s * (nch * 128);

    {   // stage W^T hi/lo
        const float4* src = (const float4*)wtp;
        float4* dst = (float4*)Wt;
#pragma unroll
        for (int i = 0; i < 9; ++i) dst[i * 512 + tid] = src[i * 512 + tid];
    }

    f32x4 kva[4][4];
#pragma unroll
    for (int a = 0; a < 4; ++a)
#pragma unroll
        for (int c2 = 0; c2 < 4; ++c2) { f32x4 z4 = {0.f,0.f,0.f,0.f}; kva[a][c2] = z4; }
    float ksa[4] = {0.f, 0.f, 0.f, 0.f};

    // prologue prefetch (chunk 0): 4x32 rows of k AND v (full 128-row chunk)
    const int tRow = tid >> 4;          // 0..31
    const int c4   = (tid & 15) * 4;
    float4 kpre[4], vpre[4];
    float  mkp[4];
#pragma unroll
    for (int p = 0; p < 4; ++p) {
        int t = p * 32 + tRow;
        kpre[p] = *(const float4*)&kg[(rowb + tcb + t) * 64 + c4];
        vpre[p] = *(const float4*)&vg[(rowb + tcb + t) * 64 + c4];
        mkp[p]  = mg[b * T_ + tcb + t];
    }

    for (int c = 0; c < nch; ++c) {
        // ---- staging writes from prefetched regs ----
#pragma unroll
        for (int p = 0; p < 4; ++p) {       // k rows: f16 hi/lo + row norm
            int t = p * 32 + tRow;
            float4 x = kpre[p];
            float s2 = x.x*x.x + x.y*x.y + x.z*x.z + x.w*x.w;
            s2 += __shfl_xor(s2, 1); s2 += __shfl_xor(s2, 2);
            s2 += __shfl_xor(s2, 4); s2 += __shfl_xor(s2, 8);
            h16x2 h01 = pkrtz(x.x, x.y);
            h16x2 h23 = pkrtz(x.z, x.w);
            h16x2 l01 = pkrtz(x.x - (float)h01.x, x.y - (float)h01.y);
            h16x2 l23 = pkrtz(x.z - (float)h23.x, x.w - (float)h23.y);
            h16x4 hv, lv;
            hv.x = h01.x; hv.y = h01.y; hv.z = h23.x; hv.w = h23.y;
            lv.x = l01.x; lv.y = l01.y; lv.z = l23.x; lv.w = l23.y;
            *(h16x4*)&kT0[t * 72 + c4] = hv;
            *(h16x4*)&kT1[t * 72 + c4] = lv;
            if ((tid & 15) == 0) { np2[t] = 0.5f * s2; mskl[t] = mkp[p] * SCALE_; }
        }
#pragma unroll
        for (int p = 0; p < 4; ++p) {       // v rows (ALL 128): mask-scaled bf16 hi/lo, transposed
            int t = p * 32 + tRow;
            float4 x = vpre[p];
            float m = mkp[p];
            x.x *= m; x.y *= m; x.z *= m; x.w *= m;
            short h, l;
            bfsplit(x.x, h, l); vTh[(c4+0)*136 + t] = h; vTl[(c4+0)*136 + t] = l;
            bfsplit(x.y, h, l); vTh[(c4+1)*136 + t] = h; vTl[(c4+1)*136 + t] = l;
            bfsplit(x.z, h, l); vTh[(c4+2)*136 + t] = h; vTl[(c4+2)*136 + t] = l;
            bfsplit(x.w, h, l); vTh[(c4+3)*136 + t] = h; vTl[(c4+3)*136 + t] = l;
        }
        __syncthreads();

        // ---- prefetch next chunk (clamped; in flight under compute) ----
        {
            int cn = (c + 1 < nch) ? (c + 1) : c;
            long tcn = tcb + (long)cn * 128;
#pragma unroll
            for (int p = 0; p < 4; ++p) {
                int t = p * 32 + tRow;
                kpre[p] = *(const float4*)&kg[(rowb + tcn + t) * 64 + c4];
                vpre[p] = *(const float4*)&vg[(rowb + tcn + t) * 64 + c4];
                mkp[p]  = mg[b * T_ + tcn + t];
            }
        }

        // ---- proj: pr[m][n]; rows t = tg*64+m*16+{l15|4q+j}, cols r = rg*64+n*16+l15 ----
        f32x4 pr[4][4];
#pragma unroll
        for (int m = 0; m < 4; ++m)
#pragma unroll
            for (int n = 0; n < 4; ++n) { f32x4 z4 = {0.f,0.f,0.f,0.f}; pr[m][n] = z4; }

#pragma unroll
        for (int w = 0; w < 2; ++w) {
            h16x8 wbh[4], wbl[4];
#pragma unroll
            for (int n = 0; n < 4; ++n) {
                int base = (rg * 64 + n * 16 + l15) * 72 + w * 32 + q * 4;
                h16x4 a0 = *(const h16x4*)&Wt[base];
                h16x4 a1 = *(const h16x4*)&Wt[base + 16];
                h16x4 b0 = *(const h16x4*)&Wt[256 * 72 + base];
                h16x4 b1 = *(const h16x4*)&Wt[256 * 72 + base + 16];
                h16x8 hv, lv;
                hv[0]=a0.x; hv[1]=a0.y; hv[2]=a0.z; hv[3]=a0.w; hv[4]=a1.x; hv[5]=a1.y; hv[6]=a1.z; hv[7]=a1.w;
                lv[0]=b0.x; lv[1]=b0.y; lv[2]=b0.z; lv[3]=b0.w; lv[4]=b1.x; lv[5]=b1.y; lv[6]=b1.z; lv[7]=b1.w;
                wbh[n] = hv; wbl[n] = lv;
            }
#pragma unroll
            for (int m = 0; m < 4; ++m) {
                int base = (tg * 64 + m * 16 + l15) * 72 + w * 32 + q * 4;
                h16x4 a0 = *(const h16x4*)&kT0[base];
                h16x4 a1 = *(const h16x4*)&kT0[base + 16];
                h16x4 b0 = *(const h16x4*)&kT1[base];
                h16x4 b1 = *(const h16x4*)&kT1[base + 16];
                h16x8 Ah, Al;
                Ah[0]=a0.x; Ah[1]=a0.y; Ah[2]=a0.z; Ah[3]=a0.w; Ah[4]=a1.x; Ah[5]=a1.y; Ah[6]=a1.z; Ah[7]=a1.w;
                Al[0]=b0.x; Al[1]=b0.y; Al[2]=b0.z; Al[3]=b0.w; Al[4]=b1.x; Al[5]=b1.y; Al[6]=b1.z; Al[7]=b1.w;
#pragma unroll
                for (int n = 0; n < 4; ++n) {
                    pr[m][n] = __builtin_amdgcn_mfma_f32_16x16x32_f16(Ah, wbh[n], pr[m][n], 0, 0, 0);
                    pr[m][n] = __builtin_amdgcn_mfma_f32_16x16x32_f16(Ah, wbl[n], pr[m][n], 0, 0, 0);
                    pr[m][n] = __builtin_amdgcn_mfma_f32_16x16x32_f16(Al, wbh[n], pr[m][n], 0, 0, 0);
                }
            }
        }

        // ---- exp + mask + bf16 split pack; then kv MFMAs per 32-t window ----
#pragma unroll
        for (int W = 0; W < 2; ++W) {
            const int m0 = 2 * W, m1 = 2 * W + 1;
            const int rb0 = tg * 64 + m0 * 16 + q * 4;
            float4 nq0 = *(const float4*)&np2[rb0];
            float4 nq1 = *(const float4*)&np2[rb0 + 16];
            float4 sm0 = *(const float4*)&mskl[rb0];
            float4 sm1 = *(const float4*)&mskl[rb0 + 16];
            bf16x8 aph[4], apl[4];
#pragma unroll
            for (int n = 0; n < 4; ++n) {
                float e0[4], e1[4];
                e0[0] = __expf(pr[m0][n][0] - nq0.x) * sm0.x;
                e0[1] = __expf(pr[m0][n][1] - nq0.y) * sm0.y;
                e0[2] = __expf(pr[m0][n][2] - nq0.z) * sm0.z;
                e0[3] = __expf(pr[m0][n][3] - nq0.w) * sm0.w;
                e1[0] = __expf(pr[m1][n][0] - nq1.x) * sm1.x;
                e1[1] = __expf(pr[m1][n][1] - nq1.y) * sm1.y;
                e1[2] = __expf(pr[m1][n][2] - nq1.z) * sm1.z;
                e1[3] = __expf(pr[m1][n][3] - nq1.w) * sm1.w;
                ksa[n] += e0[0]+e0[1]+e0[2]+e0[3]+e1[0]+e1[1]+e1[2]+e1[3];
                unsigned r0,r1,r2,r3,r4,r5,r6,r7;
                unsigned h01 = pk_hi2(e0[0], e0[1], r0, r1);
                unsigned h23 = pk_hi2(e0[2], e0[3], r2, r3);
                unsigned h45 = pk_hi2(e1[0], e1[1], r4, r5);
                unsigned h67 = pk_hi2(e1[2], e1[3], r6, r7);
                unsigned l01 = pk_tr2(e0[0]-__uint_as_float(r0), e0[1]-__uint_as_float(r1));
                unsigned l23 = pk_tr2(e0[2]-__uint_as_float(r2), e0[3]-__uint_as_float(r3));
                unsigned l45 = pk_tr2(e1[0]-__uint_as_float(r4), e1[1]-__uint_as_float(r5));
                unsigned l67 = pk_tr2(e1[2]-__uint_as_float(r6), e1[3]-__uint_as_float(r7));
                union { unsigned u[4]; bf16x8 v; } uh, ul;
                uh.u[0]=h01; uh.u[1]=h23; uh.u[2]=h45; uh.u[3]=h67;
                ul.u[0]=l01; ul.u[1]=l23; ul.u[2]=l45; ul.u[3]=l67;
                aph[n] = uh.v; apl[n] = ul.v;
            }
            bf16x8 bvh[4], bvl[4];
#pragma unroll
            for (int nd = 0; nd < 4; ++nd) {
                int base = (nd * 16 + l15) * 136 + tg * 64 + W * 32 + q * 4;
                short4v a0 = *(const short4v*)&vTh[base];
                short4v a1 = *(const short4v*)&vTh[base + 16];
                short4v b0 = *(const short4v*)&vTl[base];
                short4v b1 = *(const short4v*)&vTl[base + 16];
                bf16x8 hv, lv;
                hv[0]=a0.x; hv[1]=a0.y; hv[2]=a0.z; hv[3]=a0.w; hv[4]=a1.x; hv[5]=a1.y; hv[6]=a1.z; hv[7]=a1.w;
                lv[0]=b0.x; lv[1]=b0.y; lv[2]=b0.z; lv[3]=b0.w; lv[4]=b1.x; lv[5]=b1.y; lv[6]=b1.z; lv[7]=b1.w;
                bvh[nd] = hv; bvl[nd] = lv;
            }
#pragma unroll
            for (int n = 0; n < 4; ++n)
#pragma unroll
                for (int nd = 0; nd < 4; ++nd) {
                    kva[n][nd] = __builtin_amdgcn_mfma_f32_16x16x32_bf16(aph[n], bvh[nd], kva[n][nd], 0, 0, 0);
                    kva[n][nd] = __builtin_amdgcn_mfma_f32_16x16x32_bf16(aph[n], bvl[nd], kva[n][nd], 0, 0, 0);
                    kva[n][nd] = __builtin_amdgcn_mfma_f32_16x16x32_bf16(apl[n], bvh[nd], kva[n][nd], 0, 0, 0);
                }
        }
        __syncthreads();   // all LDS reads done before next chunk's staging writes
    }

    // ---- block end: ksum + cross-tg kv reduce (red: 256 rows x 68) ----
#pragma unroll
    for (int n = 0; n < 4; ++n) {
        float v = ksa[n];
        v += __shfl_xor(v, 16);
        v += __shfl_xor(v, 32);
        if (q == 0) ksb[tg * 256 + rg * 64 + n * 16 + l15] = v;
    }
    if (tg == 0) {
#pragma unroll
        for (int n = 0; n < 4; ++n)
#pragma unroll
            for (int nd = 0; nd < 4; ++nd)
#pragma unroll
                for (int j = 0; j < 4; ++j)
                    red[(rg * 64 + n * 16 + q * 4 + j) * 68 + nd * 16 + l15] = kva[n][nd][j];
    }
    __syncthreads();
    if (tg == 1) {
#pragma unroll
        for (int n = 0; n < 4; ++n)
#pragma unroll
            for (int nd = 0; nd < 4; ++nd)
#pragma unroll
                for (int j = 0; j < 4; ++j)
                    red[(rg * 64 + n * 16 + q * 4 + j) * 68 + nd * 16 + l15] += kva[n][nd][j];
    }
    __syncthreads();
    {
        float* dst = kv_part + (long)(s * BH_ + bh) * (256 * 64);
#pragma unroll
        for (int i = 0; i < 8; ++i) {
            int flat = (i * 512 + tid) * 4;
            int r = flat >> 6, d = flat & 63;
            *(float4*)(dst + flat) = *(const float4*)&red[r * 68 + d];
        }
        if (tid < 256) ks_part[(long)(s * BH_ + bh) * 256 + tid] = ksb[tid] + ksb[256 + tid];
    }
}

// ============================================================
// Reduce: sum split partials; emit kv^T bf16 hi/lo [bh][pl][64 d][264 r]
// + ksum_f.  grid(4, BH), 256 thr — each block: 64 r-rows of one head.
// ============================================================
__global__ __launch_bounds__(256)
void k_reduce(const float* __restrict__ kvp, const float* __restrict__ ksp,
              short* __restrict__ kvt, float* __restrict__ ksf, int split)
{
    __shared__ __align__(16) float red2[64 * 68];
    const int tid = threadIdx.x, rq = blockIdx.x, bh = blockIdx.y;
    const long NKV4 = (long)BH_ * 256 * 64 / 4;   // 262144 float4s
#pragma unroll
    for (int i = 0; i < 4; ++i) {
        int idx4 = i * 256 + tid;
        long g = (long)bh * 4096 + rq * 1024 + idx4;
        float4 a = ((const float4*)kvp)[g];
        for (int p = 1; p < split; ++p) {
            float4 t = ((const float4*)kvp)[(long)p * NKV4 + g];
            a.x += t.x; a.y += t.y; a.z += t.z; a.w += t.w;
        }
        int flat = idx4 * 4;
        int rl = flat >> 6, d = flat & 63;
        *(float4*)&red2[rl * 68 + d] = a;
    }
    if (tid < 64) {
        float s = 0.f;
        for (int p = 0; p < split; ++p) s += ksp[(long)p * (BH_ * 256) + bh * 256 + rq * 64 + tid];
        ksf[bh * 256 + rq * 64 + tid] = s;
    }
    __syncthreads();
    short* dh = kvt + (long)bh * 33792;
    short* dl = dh + 16896;
#pragma unroll
    for (int i = 0; i < 16; ++i) {
        int flat = i * 256 + tid;
        int d = flat >> 6, rl = flat & 63;
        short h, l;
        bfsplit(red2[rl * 68 + d], h, l);
        dh[d * 264 + rq * 64 + rl] = h;
        dl[d * 264 + rq * 64 + rl] = l;
    }
}

// ============================================================
// Stage 2: t-only wave split. Each wave: 16 t-rows, full r.
// proj^T (f16x3) -> exp + z (shfl) -> out (bf16x3), zero barriers per tile.
// grid(4, BH), 512 thr, 8 tiles of 128 t per block.
// ============================================================
__global__ __launch_bounds__(512, 2)
void k_stage2(const float* __restrict__ qg, const h16* __restrict__ wtp,
              const short* __restrict__ kvt, const float* __restrict__ ksf,
              float* __restrict__ outg)
{
    __shared__ __align__(16) char smem[142336];
    h16*   Wt     = (h16*)smem;                     // [2][256*72]  73728 B
    short* kvTh   = (short*)(smem + 73728);         // [64*264]     33792 B
    short* kvTl   = (short*)(smem + 107520);        // [64*264]     33792 B
    float* ksum_l = (float*)(smem + 141312);        // [256]         1024 B

    const int tid  = threadIdx.x;
    const int lane = tid & 63, l15 = lane & 15, q = lane >> 4;
    const int wid  = tid >> 6;
    const int bh = blockIdx.y, qd = blockIdx.x;
    const long rowb = (long)bh * T_;

    {
        const float4* src = (const float4*)wtp;
        float4* dst = (float4*)Wt;
#pragma unroll
        for (int i = 0; i < 9; ++i) dst[i * 512 + tid] = src[i * 512 + tid];
        const float4* s2p = (const float4*)(kvt + (long)bh * 33792);
        float4* d2 = (float4*)kvTh;
#pragma unroll
        for (int i = 0; i < 9; ++i) { int idx = i * 512 + tid; if (idx < 4224) d2[idx] = s2p[idx]; }
        if (tid < 256) ksum_l[tid] = ksf[bh * 256 + tid];
    }
    __syncthreads();

    const int trl = wid * 16 + l15;   // wave-local t row for A/B frags

    // prologue q prefetch (tile 0)
    float4 qr[4];
    {
        long rb = (rowb + (long)qd * 1024 + trl) * 64;
        qr[0] = *(const float4*)&qg[rb + q * 4];
        qr[1] = *(const float4*)&qg[rb + 16 + q * 4];
        qr[2] = *(const float4*)&qg[rb + 32 + q * 4];
        qr[3] = *(const float4*)&qg[rb + 48 + q * 4];
    }

    for (int it = 0; it < 8; ++it) {
        const int t0 = (qd * 8 + it) * 128;
        // row norm from current q regs
        float s2 = qr[0].x*qr[0].x + qr[0].y*qr[0].y + qr[0].z*qr[0].z + qr[0].w*qr[0].w
                 + qr[1].x*qr[1].x + qr[1].y*qr[1].y + qr[1].z*qr[1].z + qr[1].w*qr[1].w
                 + qr[2].x*qr[2].x + qr[2].y*qr[2].y + qr[2].z*qr[2].z + qr[2].w*qr[2].w
                 + qr[3].x*qr[3].x + qr[3].y*qr[3].y + qr[3].z*qr[3].z + qr[3].w*qr[3].w;
        s2 += __shfl_xor(s2, 16);
        s2 += __shfl_xor(s2, 32);
        const float nrm = 0.5f * s2;

        // cvt current q -> f16 hi/lo B-frags
        h16x8 qbh[2], qbl[2];
#pragma unroll
        for (int w = 0; w < 2; ++w) {
            float4 a = qr[2 * w], b2 = qr[2 * w + 1];
            h16x2 h0 = pkrtz(a.x, a.y);
            h16x2 h1 = pkrtz(a.z, a.w);
            h16x2 h2 = pkrtz(b2.x, b2.y);
            h16x2 h3 = pkrtz(b2.z, b2.w);
            h16x2 l0 = pkrtz(a.x - (float)h0.x, a.y - (float)h0.y);
            h16x2 l1 = pkrtz(a.z - (float)h1.x, a.w - (float)h1.y);
            h16x2 l2 = pkrtz(b2.x - (float)h2.x, b2.y - (float)h2.y);
            h16x2 l3 = pkrtz(b2.z - (float)h3.x, b2.w - (float)h3.y);
            h16x8 hv, lv;
            hv[0]=h0.x; hv[1]=h0.y; hv[2]=h1.x; hv[3]=h1.y; hv[4]=h2.x; hv[5]=h2.y; hv[6]=h3.x; hv[7]=h3.y;
            lv[0]=l0.x; lv[1]=l0.y; lv[2]=l1.x; lv[3]=l1.y; lv[4]=l2.x; lv[5]=l2.y; lv[6]=l3.x; lv[7]=l3.y;
            qbh[w] = hv; qbl[w] = lv;
        }

        // prefetch next tile's q
        {
            int itn = (it + 1 < 8) ? it + 1 : it;
            long rb = (rowb + (long)(qd * 8 + itn) * 128 + trl) * 64;
            qr[0] = *(const float4*)&qg[rb + q * 4];
            qr[1] = *(const float4*)&qg[rb + 16 + q * 4];
            qr[2] = *(const float4*)&qg[rb + 32 + q * 4];
            qr[3] = *(const float4*)&qg[rb + 48 + q * 4];
        }

        // proj^T: pr[m] rows r = m*16+{l15|4q+j}, col t = trl
        f32x4 pr[16];
#pragma unroll
        for (int m = 0; m < 16; ++m) { f32x4 z4 = {0.f,0.f,0.f,0.f}; pr[m] = z4; }
#pragma unroll
        for (int w = 0; w < 2; ++w) {
#pragma unroll
            for (int m = 0; m < 16; ++m) {
                int base = (m * 16 + l15) * 72 + w * 32 + q * 4;
                h16x4 a0 = *(const h16x4*)&Wt[base];
                h16x4 a1 = *(const h16x4*)&Wt[base + 16];
                h16x4 b0 = *(const h16x4*)&Wt[256 * 72 + base];
                h16x4 b1 = *(const h16x4*)&Wt[256 * 72 + base + 16];
                h16x8 Ah, Al;
                Ah[0]=a0.x; Ah[1]=a0.y; Ah[2]=a0.z; Ah[3]=a0.w; Ah[4]=a1.x; Ah[5]=a1.y; Ah[6]=a1.z; Ah[7]=a1.w;
                Al[0]=b0.x; Al[1]=b0.y; Al[2]=b0.z; Al[3]=b0.w; Al[4]=b1.x; Al[5]=b1.y; Al[6]=b1.z; Al[7]=b1.w;
                pr[m] = __builtin_amdgcn_mfma_f32_16x16x32_f16(Ah, qbh[w], pr[m], 0, 0, 0);
                pr[m] = __builtin_amdgcn_mfma_f32_16x16x32_f16(Ah, qbl[w], pr[m], 0, 0, 0);
                pr[m] = __builtin_amdgcn_mfma_f32_16x16x32_f16(Al, qbh[w], pr[m], 0, 0, 0);
            }
        }

        // exp + z + out GEMM per 32-r window
        f32x4 oac[4];
#pragma unroll
        for (int nd = 0; nd < 4; ++nd) { f32x4 z4 = {0.f,0.f,0.f,0.f}; oac[nd] = z4; }
        float z = 0.f;
#pragma unroll
        for (int W = 0; W < 8; ++W) {
            const int m0 = 2 * W, m1 = 2 * W + 1;
            float4 ka = *(const float4*)&ksum_l[m0 * 16 + q * 4];
            float4 kb = *(const float4*)&ksum_l[m1 * 16 + q * 4];
            float e0[4], e1[4];
            e0[0] = __expf(pr[m0][0] - nrm) * SCALE_;
            e0[1] = __expf(pr[m0][1] - nrm) * SCALE_;
            e0[2] = __expf(pr[m0][2] - nrm) * SCALE_;
            e0[3] = __expf(pr[m0][3] - nrm) * SCALE_;
            e1[0] = __expf(pr[m1][0] - nrm) * SCALE_;
            e1[1] = __expf(pr[m1][1] - nrm) * SCALE_;
            e1[2] = __expf(pr[m1][2] - nrm) * SCALE_;
            e1[3] = __expf(pr[m1][3] - nrm) * SCALE_;
            z += e0[0]*ka.x + e0[1]*ka.y + e0[2]*ka.z + e0[3]*ka.w
               + e1[0]*kb.x + e1[1]*kb.y + e1[2]*kb.z + e1[3]*kb.w;
            unsigned r0,r1,r2,r3,r4,r5,r6,r7;
            unsigned h01 = pk_hi2(e0[0], e0[1], r0, r1);
            unsigned h23 = pk_hi2(e0[2], e0[3], r2, r3);
            unsigned h45 = pk_hi2(e1[0], e1[1], r4, r5);
            unsigned h67 = pk_hi2(e1[2], e1[3], r6, r7);
            unsigned l01 = pk_tr2(e0[0]-__uint_as_float(r0), e0[1]-__uint_as_float(r1));
            unsigned l23 = pk_tr2(e0[2]-__uint_as_float(r2), e0[3]-__uint_as_float(r3));
            unsigned l45 = pk_tr2(e1[0]-__uint_as_float(r4), e1[1]-__uint_as_float(r5));
            unsigned l67 = pk_tr2(e1[2]-__uint_as_float(r6), e1[3]-__uint_as_float(r7));
            union { unsigned u[4]; bf16x8 v; } uh, ul;
            uh.u[0]=h01; uh.u[1]=h23; uh.u[2]=h45; uh.u[3]=h67;
            ul.u[0]=l01; ul.u[1]=l23; ul.u[2]=l45; ul.u[3]=l67;
            bf16x8 afh = uh.v, afl = ul.v;
#pragma unroll
            for (int nd = 0; nd < 4; ++nd) {
                int base = (nd * 16 + l15) * 264 + W * 32 + q * 4;
                short4v a0 = *(const short4v*)&kvTh[base];
                short4v a1 = *(const short4v*)&kvTh[base + 16];
                short4v b0 = *(const short4v*)&kvTl[base];
                short4v b1 = *(const short4v*)&kvTl[base + 16];
                bf16x8 hv, lv;
                hv[0]=a0.x; hv[1]=a0.y; hv[2]=a0.z; hv[3]=a0.w; hv[4]=a1.x; hv[5]=a1.y; hv[6]=a1.z; hv[7]=a1.w;
                lv[0]=b0.x; lv[1]=b0.y; lv[2]=b0.z; lv[3]=b0.w; lv[4]=b1.x; lv[5]=b1.y; lv[6]=b1.z; lv[7]=b1.w;
                oac[nd] = __builtin_amdgcn_mfma_f32_16x16x32_bf16(afh, hv, oac[nd], 0, 0, 0);
                oac[nd] = __builtin_amdgcn_mfma_f32_16x16x32_bf16(afh, lv, oac[nd], 0, 0, 0);
                oac[nd] = __builtin_amdgcn_mfma_f32_16x16x32_bf16(afl, hv, oac[nd], 0, 0, 0);
            }
        }

        // z reduce across r, then divide + store
        z += __shfl_xor(z, 16);
        z += __shfl_xor(z, 32);
        float rz[4];
#pragma unroll
        for (int j = 0; j < 4; ++j) {
            float zj = __shfl(z, q * 4 + j);
            rz[j] = 1.f / (zj + EPS_);
        }
#pragma unroll
        for (int j = 0; j < 4; ++j) {
            long ro = (rowb + t0 + wid * 16 + 4 * q + j) * 64 + l15;
            outg[ro]      = oac[0][j] * rz[j];
            outg[ro + 16] = oac[1][j] * rz[j];
            outg[ro + 32] = oac[2][j] * rz[j];
            outg[ro + 48] = oac[3][j] * rz[j];
        }
    }
}

// ============================================================
extern "C" void kernel_launch(void* const* d_in, const int* in_sizes, int n_in,
                              void* d_out, int out_size, void* d_ws, size_t ws_size,
                              hipStream_t stream)
{
    const float* q  = (const float*)d_in[0];
    const float* k  = (const float*)d_in[1];
    const float* v  = (const float*)d_in[2];
    const float* m  = (const float*)d_in[3];
    const float* W  = (const float*)d_in[4];
    float* out = (float*)d_out;

    char* ws = (char*)d_ws;
    h16*   wtp = (h16*)ws;                                   // 73728 B
    short* kvt = (short*)(ws + 73728);                       // 4325376 B
    float* ksf = (float*)(ws + 73728 + 4325376);             // 65536 B

    int split = 4;
    while (split > 1) {
        size_t need = 73728ull + 4325376ull + 65536ull
                    + (size_t)split * (4194304ull + 65536ull);
        if (need <= ws_size) break;
        split >>= 1;
    }
    float* kvp = (float*)(ws + 73728 + 4325376 + 65536);
    float* ksp = kvp + (size_t)split * (256 * 64 * BH_);
    int nch = (T_ / split) / 128;

    k_prep  <<<dim3(64),        dim3(256), 0, stream>>>(W, wtp);
    k_stage1<<<dim3(split, BH_), dim3(512), 0, stream>>>(k, v, m, wtp, kvp, ksp, nch);
    k_reduce<<<dim3(4, BH_),    dim3(256), 0, stream>>>(kvp, ksp, kvt, ksf, split);
    k_stage2<<<dim3(4, BH_),    dim3(512), 0, stream>>>(q, wtp, kvt, ksf, out);
}

// Round 6
// 643.655 us; speedup vs baseline: 1.1341x; 1.1341x over previous
//
#include <hip/hip_runtime.h>
#include <math.h>

#define T_     4096
#define BH_    64
#define EPS_   1e-6f
#define SCALE_ 0.0625f   // 1/sqrt(256)

typedef _Float16 h16;
typedef __attribute__((ext_vector_type(2))) _Float16 h16x2;
typedef __attribute__((ext_vector_type(4))) _Float16 h16x4;
typedef __attribute__((ext_vector_type(8))) _Float16 h16x8;
typedef __attribute__((ext_vector_type(2))) __fp16   fp16x2r;   // raw builtin return type
typedef __attribute__((ext_vector_type(4))) short    short4v;
typedef __attribute__((ext_vector_type(8))) short    bf16x8;
typedef __attribute__((ext_vector_type(4))) float    f32x4;

__device__ __forceinline__ h16x2 pkrtz(float a, float b) {
    fp16x2r r = __builtin_amdgcn_cvt_pkrtz(a, b);
    h16x2 o; o.x = (h16)r.x; o.y = (h16)r.y;
    return o;
}

__device__ __forceinline__ void bfsplit(float x, short& h, short& l) {
    unsigned u = __float_as_uint(x) + 0x8000u;       // round-half-up to bf16
    unsigned hb = u & 0xffff0000u;
    h = (short)(u >> 16);
    float lf = x - __uint_as_float(hb);              // exact residual
    l = (short)(__float_as_uint(lf) >> 16);          // truncated residual
}
// pack bf16(a) (low) | bf16(b) (high), round-half-up; returns residual bit patterns
__device__ __forceinline__ unsigned pk_hi2(float a, float b, unsigned& ra, unsigned& rb) {
    unsigned ua = __float_as_uint(a) + 0x8000u;
    unsigned ub = __float_as_uint(b) + 0x8000u;
    ra = ua & 0xffff0000u; rb = ub & 0xffff0000u;
    return __builtin_amdgcn_perm(ub, ua, 0x07060302u);
}
__device__ __forceinline__ unsigned pk_tr2(float a, float b) {   // truncating pack
    return __builtin_amdgcn_perm(__float_as_uint(b), __float_as_uint(a), 0x07060302u);
}

// ============================================================
// prep: W (64x256) -> W^T padded f16 hi/lo planes [256][72]
// ============================================================
__global__ __launch_bounds__(256)
void k_prep(const float* __restrict__ Wg, h16* __restrict__ wtp)
{
    int d = blockIdx.x;      // 0..63
    int r = threadIdx.x;     // 0..255
    float x = Wg[d * 256 + r];
    h16 hi = (h16)x;
    h16 lo = (h16)(x - (float)hi);
    wtp[r * 72 + d]            = hi;
    wtp[256 * 72 + r * 72 + d] = lo;
}

// ============================================================
// Stage 1: per (t-chunk s, head bh). k,v staged to LDS (split/bf16-split),
// proj f16x3 MFMA -> exp -> kv bf16x3 MFMA. Inline staging (no reg
// prefetch — bounded VGPR pressure). 8 waves: (tg 0..1) x (rg 0..3).
// 2 barriers/chunk.
// ============================================================
__global__ __launch_bounds__(512, 2)
void k_stage1(const float* __restrict__ kg, const float* __restrict__ vg,
              const float* __restrict__ mg, const h16* __restrict__ wtp,
              float* __restrict__ kv_part, float* __restrict__ ks_part, int nch)
{
    __shared__ __align__(16) char smem[148480];
    h16*   Wt   = (h16*)smem;                       // [2][256*72]   73728 B
    h16*   kT0  = (h16*)(smem + 73728);             // [128*72]      18432 B
    h16*   kT1  = (h16*)(smem + 92160);             // [128*72]      18432 B
    short* vTh  = (short*)(smem + 110592);          // [64*136]      17408 B
    short* vTl  = (short*)(smem + 128000);          // [64*136]      17408 B
    float* np2  = (float*)(smem + 145408);          // [128]           512 B
    float* mskl = (float*)(smem + 145920);          // [128]           512 B
    float* ksb  = (float*)(smem + 146432);          // [2][256]       2048 B
    float* red  = (float*)(smem + 73728);           // alias kT/vT: 256*68*4 = 69632 B

    const int tid  = threadIdx.x;
    const int lane = tid & 63, l15 = lane & 15, q = lane >> 4;
    const int wid  = tid >> 6;
    const int rg = wid & 3, tg = wid >> 2;
    const int s = blockIdx.x, bh = blockIdx.y, b = bh >> 4;
    const long rowb = (long)bh * T_;
    const int tcb = s * (nch * 128);

    {   // stage W^T hi/lo
        const float4* src = (const float4*)wtp;
        float4* dst = (float4*)Wt;
#pragma unroll
        for (int i = 0; i < 9; ++i) dst[i * 512 + tid] = src[i * 512 + tid];
    }

    f32x4 kva[4][4];
#pragma unroll
    for (int a = 0; a < 4; ++a)
#pragma unroll
        for (int c2 = 0; c2 < 4; ++c2) { f32x4 z4 = {0.f,0.f,0.f,0.f}; kva[a][c2] = z4; }
    float ksa[4] = {0.f, 0.f, 0.f, 0.f};

    const int tRow = tid >> 4;          // 0..31
    const int c4   = (tid & 15) * 4;

    for (int c = 0; c < nch; ++c) {
        const long tcc = tcb + (long)c * 128;
        __syncthreads();   // prev chunk fully consumed; Wt staged (c==0)

        // ---- inline staging: k (f16 hi/lo + norms) and v (bf16 hi/lo, masked) ----
#pragma unroll
        for (int p = 0; p < 4; ++p) {
            int t = p * 32 + tRow;
            float4 xk = *(const float4*)&kg[(rowb + tcc + t) * 64 + c4];
            float4 xv = *(const float4*)&vg[(rowb + tcc + t) * 64 + c4];
            float  mk = mg[b * T_ + tcc + t];

            float s2 = xk.x*xk.x + xk.y*xk.y + xk.z*xk.z + xk.w*xk.w;
            s2 += __shfl_xor(s2, 1); s2 += __shfl_xor(s2, 2);
            s2 += __shfl_xor(s2, 4); s2 += __shfl_xor(s2, 8);
            h16x2 h01 = pkrtz(xk.x, xk.y);
            h16x2 h23 = pkrtz(xk.z, xk.w);
            h16x2 l01 = pkrtz(xk.x - (float)h01.x, xk.y - (float)h01.y);
            h16x2 l23 = pkrtz(xk.z - (float)h23.x, xk.w - (float)h23.y);
            h16x4 hv, lv;
            hv.x = h01.x; hv.y = h01.y; hv.z = h23.x; hv.w = h23.y;
            lv.x = l01.x; lv.y = l01.y; lv.z = l23.x; lv.w = l23.y;
            *(h16x4*)&kT0[t * 72 + c4] = hv;
            *(h16x4*)&kT1[t * 72 + c4] = lv;
            if ((tid & 15) == 0) { np2[t] = 0.5f * s2; mskl[t] = mk * SCALE_; }

            xv.x *= mk; xv.y *= mk; xv.z *= mk; xv.w *= mk;
            short h, l;
            bfsplit(xv.x, h, l); vTh[(c4+0)*136 + t] = h; vTl[(c4+0)*136 + t] = l;
            bfsplit(xv.y, h, l); vTh[(c4+1)*136 + t] = h; vTl[(c4+1)*136 + t] = l;
            bfsplit(xv.z, h, l); vTh[(c4+2)*136 + t] = h; vTl[(c4+2)*136 + t] = l;
            bfsplit(xv.w, h, l); vTh[(c4+3)*136 + t] = h; vTl[(c4+3)*136 + t] = l;
        }
        __syncthreads();

        // ---- proj: pr[m][n]; rows t = tg*64+m*16+{l15|4q+j}, cols r = rg*64+n*16+l15 ----
        f32x4 pr[4][4];
#pragma unroll
        for (int m = 0; m < 4; ++m)
#pragma unroll
            for (int n = 0; n < 4; ++n) { f32x4 z4 = {0.f,0.f,0.f,0.f}; pr[m][n] = z4; }

#pragma unroll
        for (int w = 0; w < 2; ++w) {
            h16x8 wbh[4], wbl[4];
#pragma unroll
            for (int n = 0; n < 4; ++n) {
                int base = (rg * 64 + n * 16 + l15) * 72 + w * 32 + q * 4;
                h16x4 a0 = *(const h16x4*)&Wt[base];
                h16x4 a1 = *(const h16x4*)&Wt[base + 16];
                h16x4 b0 = *(const h16x4*)&Wt[256 * 72 + base];
                h16x4 b1 = *(const h16x4*)&Wt[256 * 72 + base + 16];
                h16x8 hv, lv;
                hv[0]=a0.x; hv[1]=a0.y; hv[2]=a0.z; hv[3]=a0.w; hv[4]=a1.x; hv[5]=a1.y; hv[6]=a1.z; hv[7]=a1.w;
                lv[0]=b0.x; lv[1]=b0.y; lv[2]=b0.z; lv[3]=b0.w; lv[4]=b1.x; lv[5]=b1.y; lv[6]=b1.z; lv[7]=b1.w;
                wbh[n] = hv; wbl[n] = lv;
            }
#pragma unroll
            for (int m = 0; m < 4; ++m) {
                int base = (tg * 64 + m * 16 + l15) * 72 + w * 32 + q * 4;
                h16x4 a0 = *(const h16x4*)&kT0[base];
                h16x4 a1 = *(const h16x4*)&kT0[base + 16];
                h16x4 b0 = *(const h16x4*)&kT1[base];
                h16x4 b1 = *(const h16x4*)&kT1[base + 16];
                h16x8 Ah, Al;
                Ah[0]=a0.x; Ah[1]=a0.y; Ah[2]=a0.z; Ah[3]=a0.w; Ah[4]=a1.x; Ah[5]=a1.y; Ah[6]=a1.z; Ah[7]=a1.w;
                Al[0]=b0.x; Al[1]=b0.y; Al[2]=b0.z; Al[3]=b0.w; Al[4]=b1.x; Al[5]=b1.y; Al[6]=b1.z; Al[7]=b1.w;
#pragma unroll
                for (int n = 0; n < 4; ++n) {
                    pr[m][n] = __builtin_amdgcn_mfma_f32_16x16x32_f16(Ah, wbh[n], pr[m][n], 0, 0, 0);
                    pr[m][n] = __builtin_amdgcn_mfma_f32_16x16x32_f16(Ah, wbl[n], pr[m][n], 0, 0, 0);
                    pr[m][n] = __builtin_amdgcn_mfma_f32_16x16x32_f16(Al, wbh[n], pr[m][n], 0, 0, 0);
                }
            }
        }

        // ---- exp + mask + bf16 split pack; then kv MFMAs per 32-t window ----
#pragma unroll
        for (int W = 0; W < 2; ++W) {
            const int m0 = 2 * W, m1 = 2 * W + 1;
            const int rb0 = tg * 64 + m0 * 16 + q * 4;
            float4 nq0 = *(const float4*)&np2[rb0];
            float4 nq1 = *(const float4*)&np2[rb0 + 16];
            float4 sm0 = *(const float4*)&mskl[rb0];
            float4 sm1 = *(const float4*)&mskl[rb0 + 16];
            bf16x8 aph[4], apl[4];
#pragma unroll
            for (int n = 0; n < 4; ++n) {
                float e0[4], e1[4];
                e0[0] = __expf(pr[m0][n][0] - nq0.x) * sm0.x;
                e0[1] = __expf(pr[m0][n][1] - nq0.y) * sm0.y;
                e0[2] = __expf(pr[m0][n][2] - nq0.z) * sm0.z;
                e0[3] = __expf(pr[m0][n][3] - nq0.w) * sm0.w;
                e1[0] = __expf(pr[m1][n][0] - nq1.x) * sm1.x;
                e1[1] = __expf(pr[m1][n][1] - nq1.y) * sm1.y;
                e1[2] = __expf(pr[m1][n][2] - nq1.z) * sm1.z;
                e1[3] = __expf(pr[m1][n][3] - nq1.w) * sm1.w;
                ksa[n] += e0[0]+e0[1]+e0[2]+e0[3]+e1[0]+e1[1]+e1[2]+e1[3];
                unsigned r0,r1,r2,r3,r4,r5,r6,r7;
                unsigned h01 = pk_hi2(e0[0], e0[1], r0, r1);
                unsigned h23 = pk_hi2(e0[2], e0[3], r2, r3);
                unsigned h45 = pk_hi2(e1[0], e1[1], r4, r5);
                unsigned h67 = pk_hi2(e1[2], e1[3], r6, r7);
                unsigned l01 = pk_tr2(e0[0]-__uint_as_float(r0), e0[1]-__uint_as_float(r1));
                unsigned l23 = pk_tr2(e0[2]-__uint_as_float(r2), e0[3]-__uint_as_float(r3));
                unsigned l45 = pk_tr2(e1[0]-__uint_as_float(r4), e1[1]-__uint_as_float(r5));
                unsigned l67 = pk_tr2(e1[2]-__uint_as_float(r6), e1[3]-__uint_as_float(r7));
                union { unsigned u[4]; bf16x8 v; } uh, ul;
                uh.u[0]=h01; uh.u[1]=h23; uh.u[2]=h45; uh.u[3]=h67;
                ul.u[0]=l01; ul.u[1]=l23; ul.u[2]=l45; ul.u[3]=l67;
                aph[n] = uh.v; apl[n] = ul.v;
            }
            bf16x8 bvh[4], bvl[4];
#pragma unroll
            for (int nd = 0; nd < 4; ++nd) {
                int base = (nd * 16 + l15) * 136 + tg * 64 + W * 32 + q * 4;
                short4v a0 = *(const short4v*)&vTh[base];
                short4v a1 = *(const short4v*)&vTh[base + 16];
                short4v b0 = *(const short4v*)&vTl[base];
                short4v b1 = *(const short4v*)&vTl[base + 16];
                bf16x8 hv, lv;
                hv[0]=a0.x; hv[1]=a0.y; hv[2]=a0.z; hv[3]=a0.w; hv[4]=a1.x; hv[5]=a1.y; hv[6]=a1.z; hv[7]=a1.w;
                lv[0]=b0.x; lv[1]=b0.y; lv[2]=b0.z; lv[3]=b0.w; lv[4]=b1.x; lv[5]=b1.y; lv[6]=b1.z; lv[7]=b1.w;
                bvh[nd] = hv; bvl[nd] = lv;
            }
#pragma unroll
            for (int n = 0; n < 4; ++n)
#pragma unroll
                for (int nd = 0; nd < 4; ++nd) {
                    kva[n][nd] = __builtin_amdgcn_mfma_f32_16x16x32_bf16(aph[n], bvh[nd], kva[n][nd], 0, 0, 0);
                    kva[n][nd] = __builtin_amdgcn_mfma_f32_16x16x32_bf16(aph[n], bvl[nd], kva[n][nd], 0, 0, 0);
                    kva[n][nd] = __builtin_amdgcn_mfma_f32_16x16x32_bf16(apl[n], bvh[nd], kva[n][nd], 0, 0, 0);
                }
        }
    }

    // ---- block end: ksum + cross-tg kv reduce (red: 256 rows x 68) ----
    __syncthreads();
#pragma unroll
    for (int n = 0; n < 4; ++n) {
        float v = ksa[n];
        v += __shfl_xor(v, 16);
        v += __shfl_xor(v, 32);
        if (q == 0) ksb[tg * 256 + rg * 64 + n * 16 + l15] = v;
    }
    if (tg == 0) {
#pragma unroll
        for (int n = 0; n < 4; ++n)
#pragma unroll
            for (int nd = 0; nd < 4; ++nd)
#pragma unroll
                for (int j = 0; j < 4; ++j)
                    red[(rg * 64 + n * 16 + q * 4 + j) * 68 + nd * 16 + l15] = kva[n][nd][j];
    }
    __syncthreads();
    if (tg == 1) {
#pragma unroll
        for (int n = 0; n < 4; ++n)
#pragma unroll
            for (int nd = 0; nd < 4; ++nd)
#pragma unroll
                for (int j = 0; j < 4; ++j)
                    red[(rg * 64 + n * 16 + q * 4 + j) * 68 + nd * 16 + l15] += kva[n][nd][j];
    }
    __syncthreads();
    {
        float* dst = kv_part + (long)(s * BH_ + bh) * (256 * 64);
#pragma unroll
        for (int i = 0; i < 8; ++i) {
            int flat = (i * 512 + tid) * 4;
            int r = flat >> 6, d = flat & 63;
            *(float4*)(dst + flat) = *(const float4*)&red[r * 68 + d];
        }
        if (tid < 256) ks_part[(long)(s * BH_ + bh) * 256 + tid] = ksb[tid] + ksb[256 + tid];
    }
}

// ============================================================
// Reduce: sum split partials; emit kv^T bf16 hi/lo [bh][pl][64 d][264 r]
// + ksum_f.  grid(8, BH), 256 thr — each block: 32 r-rows of one head.
// ============================================================
__global__ __launch_bounds__(256)
void k_reduce(const float* __restrict__ kvp, const float* __restrict__ ksp,
              short* __restrict__ kvt, float* __restrict__ ksf, int split)
{
    __shared__ __align__(16) float red2[32 * 68];
    const int tid = threadIdx.x, rq = blockIdx.x, bh = blockIdx.y;
    const long NKV4 = (long)BH_ * 256 * 64 / 4;   // float4 count per plane
#pragma unroll
    for (int i = 0; i < 2; ++i) {
        int idx4 = i * 256 + tid;
        long g = (long)bh * 4096 + rq * 512 + idx4;
        float4 a = ((const float4*)kvp)[g];
        for (int p = 1; p < split; ++p) {
            float4 t = ((const float4*)kvp)[(long)p * NKV4 + g];
            a.x += t.x; a.y += t.y; a.z += t.z; a.w += t.w;
        }
        int flat = idx4 * 4;
        int rl = flat >> 6, d = flat & 63;
        *(float4*)&red2[rl * 68 + d] = a;
    }
    if (tid < 32) {
        float s = 0.f;
        for (int p = 0; p < split; ++p) s += ksp[(long)p * (BH_ * 256) + bh * 256 + rq * 32 + tid];
        ksf[bh * 256 + rq * 32 + tid] = s;
    }
    __syncthreads();
    short* dh = kvt + (long)bh * 33792;
    short* dl = dh + 16896;
#pragma unroll
    for (int i = 0; i < 8; ++i) {
        int flat = i * 256 + tid;
        int d = flat >> 5, rl = flat & 31;
        short h, l;
        bfsplit(red2[rl * 68 + d], h, l);
        dh[d * 264 + rq * 32 + rl] = h;
        dl[d * 264 + rq * 32 + rl] = l;
    }
}

// ============================================================
// Stage 2: t-only wave split, r processed in 4 quarters (pr[4] live).
// proj^T (f16x3) -> exp + z -> out (bf16x3); zero barriers per tile.
// grid(4, BH), 512 thr, 8 tiles of 128 t per block.
// ============================================================
__global__ __launch_bounds__(512, 2)
void k_stage2(const float* __restrict__ qg, const h16* __restrict__ wtp,
              const short* __restrict__ kvt, const float* __restrict__ ksf,
              float* __restrict__ outg)
{
    __shared__ __align__(16) char smem[142336];
    h16*   Wt     = (h16*)smem;                     // [2][256*72]  73728 B
    short* kvTh   = (short*)(smem + 73728);         // [64*264]     33792 B
    short* kvTl   = (short*)(smem + 107520);        // [64*264]     33792 B
    float* ksum_l = (float*)(smem + 141312);        // [256]         1024 B

    const int tid  = threadIdx.x;
    const int lane = tid & 63, l15 = lane & 15, q = lane >> 4;
    const int wid  = tid >> 6;
    const int bh = blockIdx.y, qd = blockIdx.x;
    const long rowb = (long)bh * T_;

    {
        const float4* src = (const float4*)wtp;
        float4* dst = (float4*)Wt;
#pragma unroll
        for (int i = 0; i < 9; ++i) dst[i * 512 + tid] = src[i * 512 + tid];
        const float4* s2p = (const float4*)(kvt + (long)bh * 33792);
        float4* d2 = (float4*)kvTh;
#pragma unroll
        for (int i = 0; i < 9; ++i) { int idx = i * 512 + tid; if (idx < 4224) d2[idx] = s2p[idx]; }
        if (tid < 256) ksum_l[tid] = ksf[bh * 256 + tid];
    }
    __syncthreads();

    const int trl = wid * 16 + l15;   // wave-local t row for A/B frags

    for (int it = 0; it < 8; ++it) {
        const int t0 = (qd * 8 + it) * 128;

        // load this tile's q directly
        const float* qrow = &qg[(rowb + t0 + trl) * 64 + q * 4];
        float4 qr0 = *(const float4*)(qrow);
        float4 qr1 = *(const float4*)(qrow + 16);
        float4 qr2 = *(const float4*)(qrow + 32);
        float4 qr3 = *(const float4*)(qrow + 48);

        float s2 = qr0.x*qr0.x + qr0.y*qr0.y + qr0.z*qr0.z + qr0.w*qr0.w
                 + qr1.x*qr1.x + qr1.y*qr1.y + qr1.z*qr1.z + qr1.w*qr1.w
                 + qr2.x*qr2.x + qr2.y*qr2.y + qr2.z*qr2.z + qr2.w*qr2.w
                 + qr3.x*qr3.x + qr3.y*qr3.y + qr3.z*qr3.z + qr3.w*qr3.w;
        s2 += __shfl_xor(s2, 16);
        s2 += __shfl_xor(s2, 32);
        const float nrm = 0.5f * s2;

        // cvt q -> f16 hi/lo B-frags (16 regs)
        h16x8 qbh[2], qbl[2];
#pragma unroll
        for (int w = 0; w < 2; ++w) {
            float4 a = (w == 0) ? qr0 : qr2;
            float4 b2 = (w == 0) ? qr1 : qr3;
            h16x2 h0 = pkrtz(a.x, a.y);
            h16x2 h1 = pkrtz(a.z, a.w);
            h16x2 h2 = pkrtz(b2.x, b2.y);
            h16x2 h3 = pkrtz(b2.z, b2.w);
            h16x2 l0 = pkrtz(a.x - (float)h0.x, a.y - (float)h0.y);
            h16x2 l1 = pkrtz(a.z - (float)h1.x, a.w - (float)h1.y);
            h16x2 l2 = pkrtz(b2.x - (float)h2.x, b2.y - (float)h2.y);
            h16x2 l3 = pkrtz(b2.z - (float)h3.x, b2.w - (float)h3.y);
            h16x8 hv, lv;
            hv[0]=h0.x; hv[1]=h0.y; hv[2]=h1.x; hv[3]=h1.y; hv[4]=h2.x; hv[5]=h2.y; hv[6]=h3.x; hv[7]=h3.y;
            lv[0]=l0.x; lv[1]=l0.y; lv[2]=l1.x; lv[3]=l1.y; lv[4]=l2.x; lv[5]=l2.y; lv[6]=l3.x; lv[7]=l3.y;
            qbh[w] = hv; qbl[w] = lv;
        }

        f32x4 oac[4];
#pragma unroll
        for (int nd = 0; nd < 4; ++nd) { f32x4 z4 = {0.f,0.f,0.f,0.f}; oac[nd] = z4; }
        float z = 0.f;

        // ---- r quarters: proj (pr[4]) -> exp+z -> kv MFMAs ----
#pragma unroll
        for (int rq = 0; rq < 4; ++rq) {
            f32x4 pr[4];
#pragma unroll
            for (int mm = 0; mm < 4; ++mm) { f32x4 z4 = {0.f,0.f,0.f,0.f}; pr[mm] = z4; }
#pragma unroll
            for (int w = 0; w < 2; ++w) {
#pragma unroll
                for (int mm = 0; mm < 4; ++mm) {
                    int base = ((rq * 4 + mm) * 16 + l15) * 72 + w * 32 + q * 4;
                    h16x4 a0 = *(const h16x4*)&Wt[base];
                    h16x4 a1 = *(const h16x4*)&Wt[base + 16];
                    h16x4 b0 = *(const h16x4*)&Wt[256 * 72 + base];
                    h16x4 b1 = *(const h16x4*)&Wt[256 * 72 + base + 16];
                    h16x8 Ah, Al;
                    Ah[0]=a0.x; Ah[1]=a0.y; Ah[2]=a0.z; Ah[3]=a0.w; Ah[4]=a1.x; Ah[5]=a1.y; Ah[6]=a1.z; Ah[7]=a1.w;
                    Al[0]=b0.x; Al[1]=b0.y; Al[2]=b0.z; Al[3]=b0.w; Al[4]=b1.x; Al[5]=b1.y; Al[6]=b1.z; Al[7]=b1.w;
                    pr[mm] = __builtin_amdgcn_mfma_f32_16x16x32_f16(Ah, qbh[w], pr[mm], 0, 0, 0);
                    pr[mm] = __builtin_amdgcn_mfma_f32_16x16x32_f16(Ah, qbl[w], pr[mm], 0, 0, 0);
                    pr[mm] = __builtin_amdgcn_mfma_f32_16x16x32_f16(Al, qbh[w], pr[mm], 0, 0, 0);
                }
            }
#pragma unroll
            for (int Wl = 0; Wl < 2; ++Wl) {
                const int Wg2 = rq * 2 + Wl;
                const int m0 = 2 * Wl, m1 = 2 * Wl + 1;
                float4 ka = *(const float4*)&ksum_l[Wg2 * 32 + q * 4];
                float4 kb = *(const float4*)&ksum_l[Wg2 * 32 + 16 + q * 4];
                float e0[4], e1[4];
                e0[0] = __expf(pr[m0][0] - nrm) * SCALE_;
                e0[1] = __expf(pr[m0][1] - nrm) * SCALE_;
                e0[2] = __expf(pr[m0][2] - nrm) * SCALE_;
                e0[3] = __expf(pr[m0][3] - nrm) * SCALE_;
                e1[0] = __expf(pr[m1][0] - nrm) * SCALE_;
                e1[1] = __expf(pr[m1][1] - nrm) * SCALE_;
                e1[2] = __expf(pr[m1][2] - nrm) * SCALE_;
                e1[3] = __expf(pr[m1][3] - nrm) * SCALE_;
                z += e0[0]*ka.x + e0[1]*ka.y + e0[2]*ka.z + e0[3]*ka.w
                   + e1[0]*kb.x + e1[1]*kb.y + e1[2]*kb.z + e1[3]*kb.w;
                unsigned r0,r1,r2,r3,r4,r5,r6,r7;
                unsigned h01 = pk_hi2(e0[0], e0[1], r0, r1);
                unsigned h23 = pk_hi2(e0[2], e0[3], r2, r3);
                unsigned h45 = pk_hi2(e1[0], e1[1], r4, r5);
                unsigned h67 = pk_hi2(e1[2], e1[3], r6, r7);
                unsigned l01 = pk_tr2(e0[0]-__uint_as_float(r0), e0[1]-__uint_as_float(r1));
                unsigned l23 = pk_tr2(e0[2]-__uint_as_float(r2), e0[3]-__uint_as_float(r3));
                unsigned l45 = pk_tr2(e1[0]-__uint_as_float(r4), e1[1]-__uint_as_float(r5));
                unsigned l67 = pk_tr2(e1[2]-__uint_as_float(r6), e1[3]-__uint_as_float(r7));
                union { unsigned u[4]; bf16x8 v; } uh, ul;
                uh.u[0]=h01; uh.u[1]=h23; uh.u[2]=h45; uh.u[3]=h67;
                ul.u[0]=l01; ul.u[1]=l23; ul.u[2]=l45; ul.u[3]=l67;
                bf16x8 afh = uh.v, afl = ul.v;
#pragma unroll
                for (int nd = 0; nd < 4; ++nd) {
                    int base = (nd * 16 + l15) * 264 + Wg2 * 32 + q * 4;
                    short4v a0 = *(const short4v*)&kvTh[base];
                    short4v a1 = *(const short4v*)&kvTh[base + 16];
                    short4v b0 = *(const short4v*)&kvTl[base];
                    short4v b1 = *(const short4v*)&kvTl[base + 16];
                    bf16x8 hv, lv;
                    hv[0]=a0.x; hv[1]=a0.y; hv[2]=a0.z; hv[3]=a0.w; hv[4]=a1.x; hv[5]=a1.y; hv[6]=a1.z; hv[7]=a1.w;
                    lv[0]=b0.x; lv[1]=b0.y; lv[2]=b0.z; lv[3]=b0.w; lv[4]=b1.x; lv[5]=b1.y; lv[6]=b1.z; lv[7]=b1.w;
                    oac[nd] = __builtin_amdgcn_mfma_f32_16x16x32_bf16(afh, hv, oac[nd], 0, 0, 0);
                    oac[nd] = __builtin_amdgcn_mfma_f32_16x16x32_bf16(afh, lv, oac[nd], 0, 0, 0);
                    oac[nd] = __builtin_amdgcn_mfma_f32_16x16x32_bf16(afl, hv, oac[nd], 0, 0, 0);
                }
            }
        }

        // z reduce across r, then divide + store
        z += __shfl_xor(z, 16);
        z += __shfl_xor(z, 32);
        float rz[4];
#pragma unroll
        for (int j = 0; j < 4; ++j) {
            float zj = __shfl(z, q * 4 + j);
            rz[j] = 1.f / (zj + EPS_);
        }
#pragma unroll
        for (int j = 0; j < 4; ++j) {
            long ro = (rowb + t0 + wid * 16 + 4 * q + j) * 64 + l15;
            outg[ro]      = oac[0][j] * rz[j];
            outg[ro + 16] = oac[1][j] * rz[j];
            outg[ro + 32] = oac[2][j] * rz[j];
            outg[ro + 48] = oac[3][j] * rz[j];
        }
    }
}

// ============================================================
extern "C" void kernel_launch(void* const* d_in, const int* in_sizes, int n_in,
                              void* d_out, int out_size, void* d_ws, size_t ws_size,
                              hipStream_t stream)
{
    const float* q  = (const float*)d_in[0];
    const float* k  = (const float*)d_in[1];
    const float* v  = (const float*)d_in[2];
    const float* m  = (const float*)d_in[3];
    const float* W  = (const float*)d_in[4];
    float* out = (float*)d_out;

    char* ws = (char*)d_ws;
    h16*   wtp = (h16*)ws;                                   // 73728 B
    short* kvt = (short*)(ws + 73728);                       // 4325376 B
    float* ksf = (float*)(ws + 73728 + 4325376);             // 65536 B

    int split = 4;
    while (split > 1) {
        size_t need = 73728ull + 4325376ull + 65536ull
                    + (size_t)split * (4194304ull + 65536ull);
        if (need <= ws_size) break;
        split >>= 1;
    }
    float* kvp = (float*)(ws + 73728 + 4325376 + 65536);
    float* ksp = kvp + (size_t)split * (256 * 64 * BH_);
    int nch = (T_ / split) / 128;

    k_prep  <<<dim3(64),         dim3(256), 0, stream>>>(W, wtp);
    k_stage1<<<dim3(split, BH_), dim3(512), 0, stream>>>(k, v, m, wtp, kvp, ksp, nch);
    k_reduce<<<dim3(8, BH_),     dim3(256), 0, stream>>>(kvp, ksp, kvt, ksf, split);
    k_stage2<<<dim3(4, BH_),     dim3(512), 0, stream>>>(q, wtp, kvt, ksf, out);
}